// Round 10
// baseline (242.850 us; speedup 1.0000x reference)
//
#include <hip/hip_runtime.h>
#include <math.h>

namespace {
constexpr int NIN   = 32;
constexpr int H_    = 14;
constexpr int CIN   = 8;
constexpr int C_    = 32;
constexpr int COUT  = 16;
constexpr int R_    = 288;
constexpr int W_    = 12;
constexpr int NITER = 3;
constexpr int CH    = 32;              // r per chunk
constexpr int NCH   = 9;               // 288/32
constexpr size_t XSUB = (size_t)NIN * H_ * H_ * CIN;   // x stride per batch elem
}

typedef unsigned int u32;
typedef const __attribute__((address_space(1))) u32* as1_u32p;
typedef __attribute__((address_space(3))) u32* as3_u32p;

__device__ __forceinline__ void async_copy16(const void* g, void* l) {
    __builtin_amdgcn_global_load_lds((as1_u32p)g, (as3_u32p)l, 16, 0, 0);
}
__device__ __forceinline__ float dot4(const float4 a, const float4 b) {
    return fmaf(a.x, b.x, fmaf(a.y, b.y, fmaf(a.z, b.z, a.w * b.w)));
}
// og-quad butterflies on the VALU pipe (DPP quad_perm) — keeps them off the
// busy DS pipe (R9 win). Bit-identical to shfl_xor 1/2.
__device__ __forceinline__ float dpp_add_xor1(float v) {
    int t = __builtin_amdgcn_update_dpp(0, __float_as_int(v), 0xB1, 0xF, 0xF, true);
    return v + __int_as_float(t);
}
__device__ __forceinline__ float dpp_add_xor2(float v) {
    int t = __builtin_amdgcn_update_dpp(0, __float_as_int(v), 0x4E, 0xF, 0xF, true);
    return v + __int_as_float(t);
}

// One block (512 thr) per (c, p, q), ALL 8 batch elems: W[c] staged once per
// position (L2 W-traffic halves vs R9; staging writes/thread halve). W
// streams through double-buffered LDS via global_load_lds (stage(k+1) issued
// right after the barrier certifying stage(k) -> loads fly during
// compute(k)). x is read DIRECT from global (L2-resident) — removes 36
// ds_read + 9 staging copies per thread from the binding DS pipe; xld(k+1)
// issues mid-compute(k) and is drained by the same pre-barrier vmcnt(0).
// Thread (og=tid&3, cr=(tid>>2)&31, sg=tid>>7) owns r=k*32+cr for subs
// {2sg, 2sg+1}: acc[9][2] f4 + lg[9][2] in registers (same per-thread state
// as R9 -> occupancy up, not down).
// Lessons: no forced waves/EU (R4 spill); MLP in the zero-VGPR
// global_load_lds queue (R6/R7); priors fp32 (R2); butterflies on DPP (R9).
__global__ __launch_bounds__(512)
void caps_routeA(const float* __restrict__ x,
                 const float* __restrict__ rw,
                 float* __restrict__ out)
{
    const int tid = threadIdx.x;
    const int p  = blockIdx.x / W_;
    const int q  = blockIdx.x % W_;
    const int c  = blockIdx.y;

    __shared__ float4 wbuf[2][1024];   // [buf][i(8)][cr(32)][og(4)] 16 KB each
    __shared__ float  sRed[8][2][16];  // [wave][local sub][o]
    __shared__ float  redE[8][2];      // [wave][local sub]
    __shared__ float  vS[8][16];       // [sub][o]

    const int og   = tid & 3;
    const int cr   = (tid >> 2) & 31;  // chunk-local r
    const int lane = tid & 63;
    const int wv   = tid >> 6;         // 0..7
    const int sA   = (tid >> 7) * 2;   // first sub of this thread's pair (wave-uniform)

    const float* xA = x + (size_t)sA * XSUB;
    const float4* rwcF4 = (const float4*)(rw + (size_t)c * R_ * CIN * COUT);

    float4 xv0, xv1, xv2, xv3;         // current chunk's x (2 subs x 8 floats)
    auto xld = [&](int k) {
        const int r  = k * CH + cr;
        const int n  = r / 9, rem = r - n * 9;
        const int kh = rem / 3, kw = rem - kh * 3;
        const float* xp = xA + ((n * H_ + (p + kh)) * H_ + (q + kw)) * CIN;
        xv0 = *(const float4*)xp;          xv1 = *(const float4*)(xp + 4);
        xv2 = *(const float4*)(xp + XSUB); xv3 = *(const float4*)(xp + XSUB + 4);
    };

    auto stage = [&](int k, int buf) {
        // slot s = t*512+tid -> [ii=s>>7][wcr=(s>>2)&31][wog=s&3];
        // global f4 = wcr*32 + ii*4 + wog (chunk base k*1024 f4)
        const float4* gchunk = rwcF4 + (size_t)k * (CH * 32);
        #pragma unroll
        for (int t = 0; t < 2; ++t) {
            const int s   = t * 512 + tid;
            const int ii  = s >> 7;
            const int wcr = (s >> 2) & 31;
            async_copy16(gchunk + (wcr * 32 + ii * 4 + (s & 3)),
                         (char*)&wbuf[buf][0] + (t * 512 + (tid & 448)) * 16);
        }
    };

    float4 acc[NCH][2];

    xld(0);
    stage(0, 0);
    #pragma unroll
    for (int k = 0; k < NCH; ++k) {
        __syncthreads();               // drains stage(k) + xld(k); buf[(k+1)&1] free
        if (k + 1 < NCH) stage(k + 1, (k + 1) & 1);
        const float4* wb = &wbuf[k & 1][0];
        const float fA[8] = {xv0.x, xv0.y, xv0.z, xv0.w, xv1.x, xv1.y, xv1.z, xv1.w};
        const float fB[8] = {xv2.x, xv2.y, xv2.z, xv2.w, xv3.x, xv3.y, xv3.z, xv3.w};
        if (k + 1 < NCH) xld(k + 1);   // WAR on xv after fA/fB extraction
        float4 a0 = make_float4(0.f, 0.f, 0.f, 0.f);
        float4 a1 = make_float4(0.f, 0.f, 0.f, 0.f);
        #pragma unroll
        for (int i = 0; i < 8; ++i) {
            const float4 wv4 = wb[i * 128 + cr * 4 + og];   // 64 consecutive f4/wave
            a0.x = fmaf(fA[i], wv4.x, a0.x);  a1.x = fmaf(fB[i], wv4.x, a1.x);
            a0.y = fmaf(fA[i], wv4.y, a0.y);  a1.y = fmaf(fB[i], wv4.y, a1.y);
            a0.z = fmaf(fA[i], wv4.z, a0.z);  a1.z = fmaf(fB[i], wv4.z, a1.z);
            a0.w = fmaf(fA[i], wv4.w, a0.w);  a1.w = fmaf(fB[i], wv4.w, a1.w);
        }
        acc[k][0] = a0;  acc[k][1] = a1;
    }

    float lgA[NCH], lgB[NCH];
    #pragma unroll
    for (int j = 0; j < NCH; ++j) { lgA[j] = 0.f; lgB[j] = 0.f; }

    for (int it = 0; it < NITER; ++it) {
        float4 s0 = make_float4(0.f, 0.f, 0.f, 0.f);
        float4 s1 = make_float4(0.f, 0.f, 0.f, 0.f);
        float se0 = 0.f, se1 = 0.f;

        if (it == 0) {
            #pragma unroll
            for (int j = 0; j < NCH; ++j) {
                s0.x += acc[j][0].x;  s1.x += acc[j][1].x;
                s0.y += acc[j][0].y;  s1.y += acc[j][1].y;
                s0.z += acc[j][0].z;  s1.z += acc[j][1].z;
                s0.w += acc[j][0].w;  s1.w += acc[j][1].w;
            }
        } else {
            const float4 v0 = *(const float4*)&vS[sA][og * 4];
            const float4 v1 = *(const float4*)&vS[sA + 1][og * 4];
            #pragma unroll
            for (int j = 0; j < NCH; ++j) {
                float d0 = dot4(acc[j][0], v0);
                float d1 = dot4(acc[j][1], v1);
                d0 = dpp_add_xor1(d0);  d1 = dpp_add_xor1(d1);   // VALU
                d0 = dpp_add_xor2(d0);  d1 = dpp_add_xor2(d1);
                lgA[j] += d0;                 lgB[j] += d1;
                const float e0 = __expf(lgA[j]);
                const float e1 = __expf(lgB[j]);
                se0 += e0;                    se1 += e1;
                s0.x = fmaf(e0, acc[j][0].x, s0.x);  s1.x = fmaf(e1, acc[j][1].x, s1.x);
                s0.y = fmaf(e0, acc[j][0].y, s0.y);  s1.y = fmaf(e1, acc[j][1].y, s1.y);
                s0.z = fmaf(e0, acc[j][0].z, s0.z);  s1.z = fmaf(e1, acc[j][1].z, s1.z);
                s0.w = fmaf(e0, acc[j][0].w, s0.w);  s1.w = fmaf(e1, acc[j][1].w, s1.w);
            }
            // se identical across og lanes -> reduce over lane bits 2..5 only
            #pragma unroll
            for (int off = 4; off <= 32; off <<= 1) {
                se0 += __shfl_xor(se0, off, 64);
                se1 += __shfl_xor(se1, off, 64);
            }
            if (lane == 0) { redE[wv][0] = se0; redE[wv][1] = se1; }
        }

        // reduce s over the wave's 16 cr-slots (1/sum_e folded into squash)
        #pragma unroll
        for (int off = 4; off <= 32; off <<= 1) {
            s0.x += __shfl_xor(s0.x, off, 64);  s1.x += __shfl_xor(s1.x, off, 64);
            s0.y += __shfl_xor(s0.y, off, 64);  s1.y += __shfl_xor(s1.y, off, 64);
            s0.z += __shfl_xor(s0.z, off, 64);  s1.z += __shfl_xor(s1.z, off, 64);
            s0.w += __shfl_xor(s0.w, off, 64);  s1.w += __shfl_xor(s1.w, off, 64);
        }
        if (lane < 4) {   // lane == og
            *(float4*)&sRed[wv][0][lane * 4] = s0;
            *(float4*)&sRed[wv][1][lane * 4] = s1;
        }
        __syncthreads();

        // ---- squash: 128 threads = (sub 0..7, o 0..15)
        if (tid < 128) {
            const int sub = tid >> 4;
            const int o   = tid & 15;
            const int g   = sub >> 1;      // wave-pair group
            const int l   = sub & 1;       // local sub within pair
            const float inv = (it == 0)
                ? (1.0f / (float)R_)
                : 1.0f / (redE[g * 2][l] + redE[g * 2 + 1][l]);
            float s = (sRed[g * 2][l][o] + sRed[g * 2 + 1][l][o]) * inv;
            float sn = s * s;
            sn = dpp_add_xor1(sn);
            sn = dpp_add_xor2(sn);
            sn += __shfl_xor(sn, 4, 64);
            sn += __shfl_xor(sn, 8, 64);
            const float v = s * (sqrtf(sn) / (1.0f + sn));
            if (it == NITER - 1) {
                out[((((size_t)sub * C_ + c) * W_ + p) * W_ + q) * COUT + o] = v;
            } else {
                vS[sub][o] = v;
            }
        }
        if (it == NITER - 1) break;
        __syncthreads();   // vS visible before next iteration
    }
}

extern "C" void kernel_launch(void* const* d_in, const int* in_sizes, int n_in,
                              void* d_out, int out_size, void* d_ws, size_t ws_size,
                              hipStream_t stream) {
    const float* x  = (const float*)d_in[0];
    const float* rw = (const float*)d_in[1];
    float* out = (float*)d_out;
    dim3 grid(W_ * W_, C_);
    caps_routeA<<<grid, 512, 0, stream>>>(x, rw, out);
}

// Round 11
// 222.293 us; speedup vs baseline: 1.0925x; 1.0925x over previous
//
#include <hip/hip_runtime.h>
#include <math.h>

namespace {
constexpr int NIN   = 32;
constexpr int H_    = 14;
constexpr int CIN   = 8;
constexpr int C_    = 32;
constexpr int COUT  = 16;
constexpr int R_    = 288;
constexpr int W_    = 12;
constexpr int NITER = 3;
constexpr int CH    = 32;              // r per chunk
constexpr int NCH   = 9;               // 288/32
constexpr size_t XSUB = (size_t)NIN * H_ * H_ * CIN;   // x stride per batch elem
}

typedef unsigned int u32;
typedef const __attribute__((address_space(1))) u32* as1_u32p;
typedef __attribute__((address_space(3))) u32* as3_u32p;

__device__ __forceinline__ void async_copy16(const void* g, void* l) {
    __builtin_amdgcn_global_load_lds((as1_u32p)g, (as3_u32p)l, 16, 0, 0);
}
__device__ __forceinline__ float dot4(const float4 a, const float4 b) {
    return fmaf(a.x, b.x, fmaf(a.y, b.y, fmaf(a.z, b.z, a.w * b.w)));
}
// VALU-pipe cross-lane adds (DPP) — keep reductions off the binding DS pipe.
// quad_perm xor1 = 0xB1, xor2 = 0x4E; row_shr:4 = 0x114, row_shr:8 = 0x118.
__device__ __forceinline__ float dpp_add_xor1(float v) {
    int t = __builtin_amdgcn_update_dpp(0, __float_as_int(v), 0xB1, 0xF, 0xF, true);
    return v + __int_as_float(t);
}
__device__ __forceinline__ float dpp_add_xor2(float v) {
    int t = __builtin_amdgcn_update_dpp(0, __float_as_int(v), 0x4E, 0xF, 0xF, true);
    return v + __int_as_float(t);
}
__device__ __forceinline__ float dpp_add_shr4(float v) {
    int t = __builtin_amdgcn_update_dpp(0, __float_as_int(v), 0x114, 0xF, 0xF, true);
    return v + __int_as_float(t);
}
__device__ __forceinline__ float dpp_add_shr8(float v) {
    int t = __builtin_amdgcn_update_dpp(0, __float_as_int(v), 0x118, 0xF, 0xF, true);
    return v + __int_as_float(t);
}

// One block (256 thr) per (c, b-QUAD, p, q) — R9 base. Changes vs R9:
//  (a) x read DIRECT from global (L2-resident), prefetched one chunk ahead
//      in registers: removes 36 ds_read_b128 + 9 staging writes per thread
//      from the binding DS pipe (R8/R9 analysis: DS ~75% busy).
//  (b) s/se wave-reductions: lane bits 2-3 summed via DPP row_shr4/8
//      (VALU, og-preserving, bit-identical pairwise sums); only xor16/32
//      remain as ds_swizzle. Row totals land in lanes 12..15 (og = lane&3).
// W streams through double-buffered LDS via global_load_lds; stage(k+1)
// issues right after the barrier certifying stage(k).
// Lessons: 256-thr blocks — 512-thr barriers regressed twice (R6, R10);
// no forced waves/EU (R4 spill); MLP in the zero-VGPR global_load_lds
// queue (R7); priors fp32 (R2); butterflies on DPP (R9).
__global__ __launch_bounds__(256)
void caps_routeB(const float* __restrict__ x,
                 const float* __restrict__ rw,
                 float* __restrict__ out)
{
    const int tid = threadIdx.x;
    const int p  = blockIdx.x / W_;
    const int q  = blockIdx.x % W_;
    const int b0 = blockIdx.y * 4;
    const int c  = blockIdx.z;

    __shared__ float4 wbuf[2][1024];   // [buf][i(8)][cr(32)][og(4)] 16 KB each
    __shared__ float  sRed[4][2][16];  // [wave][local sub][o]
    __shared__ float  redE[4][2];      // [wave][local sub]
    __shared__ float  vS[4][16];       // [sub][o]

    const int og   = tid & 3;
    const int rl   = tid >> 2;     // 0..63
    const int cr   = rl & 31;      // chunk-local r
    const int sh   = rl >> 5;      // wave-uniform: waves 0,1 -> subs 0,1; 2,3 -> 2,3
    const int lane = tid & 63;
    const int wv   = tid >> 6;
    const int sA   = sh * 2;       // first sub of this thread's pair

    const float* xA = x + (size_t)(b0 + sA) * XSUB;
    const float4* rwcF4 = (const float4*)(rw + (size_t)c * R_ * CIN * COUT);

    float4 xv0, xv1, xv2, xv3;     // prefetched x for the *next* chunk (2 subs)
    auto xld = [&](int k) {
        const int r  = k * CH + cr;
        const int n  = r / 9, rem = r - n * 9;
        const int kh = rem / 3, kw = rem - kh * 3;
        const float* xp = xA + ((n * H_ + (p + kh)) * H_ + (q + kw)) * CIN;
        xv0 = *(const float4*)xp;          xv1 = *(const float4*)(xp + 4);
        xv2 = *(const float4*)(xp + XSUB); xv3 = *(const float4*)(xp + XSUB + 4);
    };

    auto stage = [&](int k, int buf) {
        // slot s = t*256+tid -> [ii=s>>7][wcr=(s>>2)&31][wog=s&3];
        // global f4 = wcr*32 + ii*4 + wog (chunk base k*1024 f4)
        const float4* gchunk = rwcF4 + (size_t)k * (CH * 32);
        #pragma unroll
        for (int t = 0; t < 4; ++t) {
            const int s   = t * 256 + tid;
            const int ii  = s >> 7;
            const int wcr = (s >> 2) & 31;
            async_copy16(gchunk + (wcr * 32 + ii * 4 + (s & 3)),
                         (char*)&wbuf[buf][0] + (t * 256 + (tid & 192)) * 16);
        }
    };

    float4 acc[NCH][2];

    xld(0);
    stage(0, 0);
    #pragma unroll
    for (int k = 0; k < NCH; ++k) {
        __syncthreads();               // stage(k) drained; buf[(k+1)&1] consumed
        if (k + 1 < NCH) stage(k + 1, (k + 1) & 1);
        const float4* wb = &wbuf[k & 1][0];
        const float fA[8] = {xv0.x, xv0.y, xv0.z, xv0.w, xv1.x, xv1.y, xv1.z, xv1.w};
        const float fB[8] = {xv2.x, xv2.y, xv2.z, xv2.w, xv3.x, xv3.y, xv3.z, xv3.w};
        if (k + 1 < NCH) xld(k + 1);   // issue next x loads behind compute
        float4 a0 = make_float4(0.f, 0.f, 0.f, 0.f);
        float4 a1 = make_float4(0.f, 0.f, 0.f, 0.f);
        #pragma unroll
        for (int i = 0; i < 8; ++i) {
            const float4 wv4 = wb[i * 128 + cr * 4 + og];   // conflict-free b128
            a0.x = fmaf(fA[i], wv4.x, a0.x);  a1.x = fmaf(fB[i], wv4.x, a1.x);
            a0.y = fmaf(fA[i], wv4.y, a0.y);  a1.y = fmaf(fB[i], wv4.y, a1.y);
            a0.z = fmaf(fA[i], wv4.z, a0.z);  a1.z = fmaf(fB[i], wv4.z, a1.z);
            a0.w = fmaf(fA[i], wv4.w, a0.w);  a1.w = fmaf(fB[i], wv4.w, a1.w);
        }
        acc[k][0] = a0;  acc[k][1] = a1;
    }

    float lgA[NCH], lgB[NCH];
    #pragma unroll
    for (int j = 0; j < NCH; ++j) { lgA[j] = 0.f; lgB[j] = 0.f; }

    for (int it = 0; it < NITER; ++it) {
        float4 s0 = make_float4(0.f, 0.f, 0.f, 0.f);
        float4 s1 = make_float4(0.f, 0.f, 0.f, 0.f);
        float se0 = 0.f, se1 = 0.f;

        if (it == 0) {
            #pragma unroll
            for (int j = 0; j < NCH; ++j) {
                s0.x += acc[j][0].x;  s1.x += acc[j][1].x;
                s0.y += acc[j][0].y;  s1.y += acc[j][1].y;
                s0.z += acc[j][0].z;  s1.z += acc[j][1].z;
                s0.w += acc[j][0].w;  s1.w += acc[j][1].w;
            }
        } else {
            const float4 v0 = *(const float4*)&vS[sA][og * 4];
            const float4 v1 = *(const float4*)&vS[sA + 1][og * 4];
            #pragma unroll
            for (int j = 0; j < NCH; ++j) {
                float d0 = dot4(acc[j][0], v0);
                float d1 = dot4(acc[j][1], v1);
                d0 = dpp_add_xor1(d0);  d1 = dpp_add_xor1(d1);   // VALU
                d0 = dpp_add_xor2(d0);  d1 = dpp_add_xor2(d1);
                lgA[j] += d0;                 lgB[j] += d1;
                const float e0 = __expf(lgA[j]);
                const float e1 = __expf(lgB[j]);
                se0 += e0;                    se1 += e1;
                s0.x = fmaf(e0, acc[j][0].x, s0.x);  s1.x = fmaf(e1, acc[j][1].x, s1.x);
                s0.y = fmaf(e0, acc[j][0].y, s0.y);  s1.y = fmaf(e1, acc[j][1].y, s1.y);
                s0.z = fmaf(e0, acc[j][0].z, s0.z);  s1.z = fmaf(e1, acc[j][1].z, s1.z);
                s0.w = fmaf(e0, acc[j][0].w, s0.w);  s1.w = fmaf(e1, acc[j][1].w, s1.w);
            }
            // se: og-redundant; sum lane bits 2-3 on DPP, 4-5 on swizzle
            se0 = dpp_add_shr4(se0);  se1 = dpp_add_shr4(se1);
            se0 = dpp_add_shr8(se0);  se1 = dpp_add_shr8(se1);
            se0 += __shfl_xor(se0, 16, 64);  se1 += __shfl_xor(se1, 16, 64);
            se0 += __shfl_xor(se0, 32, 64);  se1 += __shfl_xor(se1, 32, 64);
            if (lane == 15) { redE[wv][0] = se0; redE[wv][1] = se1; }
        }

        // s-reduce over the wave's 16 cr-slots: bits 2-3 via DPP row_shr
        // (og-preserving; totals land in lanes 12..15), bits 4-5 via swizzle.
        s0.x = dpp_add_shr4(s0.x);  s1.x = dpp_add_shr4(s1.x);
        s0.y = dpp_add_shr4(s0.y);  s1.y = dpp_add_shr4(s1.y);
        s0.z = dpp_add_shr4(s0.z);  s1.z = dpp_add_shr4(s1.z);
        s0.w = dpp_add_shr4(s0.w);  s1.w = dpp_add_shr4(s1.w);
        s0.x = dpp_add_shr8(s0.x);  s1.x = dpp_add_shr8(s1.x);
        s0.y = dpp_add_shr8(s0.y);  s1.y = dpp_add_shr8(s1.y);
        s0.z = dpp_add_shr8(s0.z);  s1.z = dpp_add_shr8(s1.z);
        s0.w = dpp_add_shr8(s0.w);  s1.w = dpp_add_shr8(s1.w);
        #pragma unroll
        for (int off = 16; off <= 32; off <<= 1) {
            s0.x += __shfl_xor(s0.x, off, 64);  s1.x += __shfl_xor(s1.x, off, 64);
            s0.y += __shfl_xor(s0.y, off, 64);  s1.y += __shfl_xor(s1.y, off, 64);
            s0.z += __shfl_xor(s0.z, off, 64);  s1.z += __shfl_xor(s1.z, off, 64);
            s0.w += __shfl_xor(s0.w, off, 64);  s1.w += __shfl_xor(s1.w, off, 64);
        }
        if (lane >= 12 && lane < 16) {   // lanes 12..15, og = lane&3
            *(float4*)&sRed[wv][0][(lane & 3) * 4] = s0;
            *(float4*)&sRed[wv][1][(lane & 3) * 4] = s1;
        }
        __syncthreads();

        // ---- squash: 64 threads = (sub 0..3, o 0..15)
        if (tid < 64) {
            const int sub = tid >> 4;
            const int o   = tid & 15;
            const int g   = sub >> 1;      // wave-pair group
            const int l   = sub & 1;       // local sub within pair
            const float inv = (it == 0)
                ? (1.0f / (float)R_)
                : 1.0f / (redE[g * 2][l] + redE[g * 2 + 1][l]);
            float s = (sRed[g * 2][l][o] + sRed[g * 2 + 1][l][o]) * inv;
            float sn = s * s;
            sn = dpp_add_xor1(sn);
            sn = dpp_add_xor2(sn);
            sn += __shfl_xor(sn, 4, 64);
            sn += __shfl_xor(sn, 8, 64);
            const float v = s * (sqrtf(sn) / (1.0f + sn));
            if (it == NITER - 1) {
                out[((((size_t)(b0 + sub) * C_ + c) * W_ + p) * W_ + q) * COUT + o] = v;
            } else {
                vS[sub][o] = v;
            }
        }
        if (it == NITER - 1) break;
        __syncthreads();   // vS visible before next iteration
    }
}

extern "C" void kernel_launch(void* const* d_in, const int* in_sizes, int n_in,
                              void* d_out, int out_size, void* d_ws, size_t ws_size,
                              hipStream_t stream) {
    const float* x  = (const float*)d_in[0];
    const float* rw = (const float*)d_in[1];
    float* out = (float*)d_out;
    dim3 grid(W_ * W_, 2, C_);
    caps_routeB<<<grid, 256, 0, stream>>>(x, rw, out);
}

// Round 12
// 188.348 us; speedup vs baseline: 1.2894x; 1.1802x over previous
//
#include <hip/hip_runtime.h>
#include <math.h>

namespace {
constexpr int NIN   = 32;
constexpr int H_    = 14;
constexpr int CIN   = 8;
constexpr int C_    = 32;
constexpr int COUT  = 16;
constexpr int R_    = 288;
constexpr int W_    = 12;
constexpr int NITER = 3;
constexpr int CH    = 32;              // r per chunk
constexpr int NCH   = 9;               // 288/32
constexpr size_t XSUB = (size_t)NIN * H_ * H_ * CIN;   // x stride per batch elem
}

typedef unsigned int u32;
typedef const __attribute__((address_space(1))) u32* as1_u32p;
typedef __attribute__((address_space(3))) u32* as3_u32p;

__device__ __forceinline__ void async_copy16(const void* g, void* l) {
    __builtin_amdgcn_global_load_lds((as1_u32p)g, (as3_u32p)l, 16, 0, 0);
}
__device__ __forceinline__ float dot4(const float4 a, const float4 b) {
    return fmaf(a.x, b.x, fmaf(a.y, b.y, fmaf(a.z, b.z, a.w * b.w)));
}
// VALU-pipe cross-lane ops (DPP) — keep traffic off the binding DS pipe.
// quad_perm[a,b,c,d] ctrl = a|(b<<2)|(c<<4)|(d<<6); row_shr:N = 0x110|N.
__device__ __forceinline__ float dpp_add_xor1(float v) {
    int t = __builtin_amdgcn_update_dpp(0, __float_as_int(v), 0xB1, 0xF, 0xF, true);
    return v + __int_as_float(t);
}
__device__ __forceinline__ float dpp_add_xor2(float v) {
    int t = __builtin_amdgcn_update_dpp(0, __float_as_int(v), 0x4E, 0xF, 0xF, true);
    return v + __int_as_float(t);
}
__device__ __forceinline__ float dpp_add_shr4(float v) {
    int t = __builtin_amdgcn_update_dpp(0, __float_as_int(v), 0x114, 0xF, 0xF, true);
    return v + __int_as_float(t);
}
__device__ __forceinline__ float dpp_add_shr8(float v) {
    int t = __builtin_amdgcn_update_dpp(0, __float_as_int(v), 0x118, 0xF, 0xF, true);
    return v + __int_as_float(t);
}
template <int CTRL>
__device__ __forceinline__ float dpp_bc(float v) {   // quad broadcast (mov)
    return __int_as_float(
        __builtin_amdgcn_update_dpp(0, __float_as_int(v), CTRL, 0xF, 0xF, true));
}

// One block (256 thr) per (c, b-QUAD, p, q) — R9 skeleton. Changes:
//  (a) x path: per chunk each lane loads exactly ONE float4 from global
//      (lane og of a quad takes sub sA+(og>>1), half og&1 — same VMEM count
//      and L2 traffic as R9's staging), then the og-quad exchanges via 16
//      quad_perm broadcasts (VALU). Deletes 4 ds_reads + 1 staging write
//      per thread per chunk from the DS pipe. (R11's x-direct had 4x
//      og-redundant global loads — that was the regression.)
//  (b) s/se wave-reductions: lane bits 2-3 via DPP row_shr4/8 (VALU,
//      og-preserving, totals in lanes 12..15); only xor16/32 on swizzle.
// W streams through double-buffered LDS via global_load_lds; stage(k+1)
// issues right after the barrier certifying stage(k).
// Lessons: 256-thr blocks (512 regressed twice: R6, R10); no forced
// waves/EU (R4 spill); MLP in the zero-VGPR global_load_lds queue (R7);
// priors fp32 (R2); cross-lane on DPP where possible (R9/R11).
__global__ __launch_bounds__(256)
void caps_routeC(const float* __restrict__ x,
                 const float* __restrict__ rw,
                 float* __restrict__ out)
{
    const int tid = threadIdx.x;
    const int p  = blockIdx.x / W_;
    const int q  = blockIdx.x % W_;
    const int b0 = blockIdx.y * 4;
    const int c  = blockIdx.z;

    __shared__ float4 wbuf[2][1024];   // [buf][i(8)][cr(32)][og(4)] 16 KB each
    __shared__ float  sRed[4][2][16];  // [wave][local sub][o]
    __shared__ float  redE[4][2];      // [wave][local sub]
    __shared__ float  vS[4][16];       // [sub][o]

    const int og   = tid & 3;
    const int rl   = tid >> 2;     // 0..63
    const int cr   = rl & 31;      // chunk-local r
    const int sh   = rl >> 5;      // wave-uniform: waves 0,1 -> subs 0,1; 2,3 -> 2,3
    const int lane = tid & 63;
    const int wv   = tid >> 6;
    const int sA   = sh * 2;       // first sub of this thread's pair

    // per-lane x base: lane og covers (sub sA + (og>>1), float4-half og&1)
    const float* xq = x + (size_t)(b0 + sA + (og >> 1)) * XSUB + (og & 1) * 4;
    const float4* rwcF4 = (const float4*)(rw + (size_t)c * R_ * CIN * COUT);

    float4 xv;                     // this lane's single x float4 for cur chunk
    auto xld = [&](int k) {
        const int r  = k * CH + cr;
        const int n  = r / 9, rem = r - n * 9;
        const int kh = rem / 3, kw = rem - kh * 3;
        xv = *(const float4*)(xq + ((n * H_ + (p + kh)) * H_ + (q + kw)) * CIN);
    };

    auto stage = [&](int k, int buf) {
        // slot s = t*256+tid -> [ii=s>>7][wcr=(s>>2)&31][wog=s&3];
        // global f4 = wcr*32 + ii*4 + wog (chunk base k*1024 f4)
        const float4* gchunk = rwcF4 + (size_t)k * (CH * 32);
        #pragma unroll
        for (int t = 0; t < 4; ++t) {
            const int s   = t * 256 + tid;
            const int ii  = s >> 7;
            const int wcr = (s >> 2) & 31;
            async_copy16(gchunk + (wcr * 32 + ii * 4 + (s & 3)),
                         (char*)&wbuf[buf][0] + (t * 256 + (tid & 192)) * 16);
        }
    };

    float4 acc[NCH][2];

    xld(0);
    stage(0, 0);
    #pragma unroll
    for (int k = 0; k < NCH; ++k) {
        __syncthreads();               // stage(k)+xld(k) drained; other buf free
        if (k + 1 < NCH) stage(k + 1, (k + 1) & 1);
        const float4* wb = &wbuf[k & 1][0];
        // og-quad exchange: fA = sub sA floats 0..7, fB = sub sA+1 (VALU)
        const float4 cur = xv;
        float fA[8], fB[8];
        fA[0] = dpp_bc<0x00>(cur.x); fA[1] = dpp_bc<0x00>(cur.y);
        fA[2] = dpp_bc<0x00>(cur.z); fA[3] = dpp_bc<0x00>(cur.w);
        fA[4] = dpp_bc<0x55>(cur.x); fA[5] = dpp_bc<0x55>(cur.y);
        fA[6] = dpp_bc<0x55>(cur.z); fA[7] = dpp_bc<0x55>(cur.w);
        fB[0] = dpp_bc<0xAA>(cur.x); fB[1] = dpp_bc<0xAA>(cur.y);
        fB[2] = dpp_bc<0xAA>(cur.z); fB[3] = dpp_bc<0xAA>(cur.w);
        fB[4] = dpp_bc<0xFF>(cur.x); fB[5] = dpp_bc<0xFF>(cur.y);
        fB[6] = dpp_bc<0xFF>(cur.z); fB[7] = dpp_bc<0xFF>(cur.w);
        if (k + 1 < NCH) xld(k + 1);   // WAR on xv cleared (cur extracted)
        float4 a0 = make_float4(0.f, 0.f, 0.f, 0.f);
        float4 a1 = make_float4(0.f, 0.f, 0.f, 0.f);
        #pragma unroll
        for (int i = 0; i < 8; ++i) {
            const float4 wv4 = wb[i * 128 + cr * 4 + og];   // conflict-free b128
            a0.x = fmaf(fA[i], wv4.x, a0.x);  a1.x = fmaf(fB[i], wv4.x, a1.x);
            a0.y = fmaf(fA[i], wv4.y, a0.y);  a1.y = fmaf(fB[i], wv4.y, a1.y);
            a0.z = fmaf(fA[i], wv4.z, a0.z);  a1.z = fmaf(fB[i], wv4.z, a1.z);
            a0.w = fmaf(fA[i], wv4.w, a0.w);  a1.w = fmaf(fB[i], wv4.w, a1.w);
        }
        acc[k][0] = a0;  acc[k][1] = a1;
    }

    float lgA[NCH], lgB[NCH];
    #pragma unroll
    for (int j = 0; j < NCH; ++j) { lgA[j] = 0.f; lgB[j] = 0.f; }

    for (int it = 0; it < NITER; ++it) {
        float4 s0 = make_float4(0.f, 0.f, 0.f, 0.f);
        float4 s1 = make_float4(0.f, 0.f, 0.f, 0.f);
        float se0 = 0.f, se1 = 0.f;

        if (it == 0) {
            #pragma unroll
            for (int j = 0; j < NCH; ++j) {
                s0.x += acc[j][0].x;  s1.x += acc[j][1].x;
                s0.y += acc[j][0].y;  s1.y += acc[j][1].y;
                s0.z += acc[j][0].z;  s1.z += acc[j][1].z;
                s0.w += acc[j][0].w;  s1.w += acc[j][1].w;
            }
        } else {
            const float4 v0 = *(const float4*)&vS[sA][og * 4];
            const float4 v1 = *(const float4*)&vS[sA + 1][og * 4];
            #pragma unroll
            for (int j = 0; j < NCH; ++j) {
                float d0 = dot4(acc[j][0], v0);
                float d1 = dot4(acc[j][1], v1);
                d0 = dpp_add_xor1(d0);  d1 = dpp_add_xor1(d1);   // VALU
                d0 = dpp_add_xor2(d0);  d1 = dpp_add_xor2(d1);
                lgA[j] += d0;                 lgB[j] += d1;
                const float e0 = __expf(lgA[j]);
                const float e1 = __expf(lgB[j]);
                se0 += e0;                    se1 += e1;
                s0.x = fmaf(e0, acc[j][0].x, s0.x);  s1.x = fmaf(e1, acc[j][1].x, s1.x);
                s0.y = fmaf(e0, acc[j][0].y, s0.y);  s1.y = fmaf(e1, acc[j][1].y, s1.y);
                s0.z = fmaf(e0, acc[j][0].z, s0.z);  s1.z = fmaf(e1, acc[j][1].z, s1.z);
                s0.w = fmaf(e0, acc[j][0].w, s0.w);  s1.w = fmaf(e1, acc[j][1].w, s1.w);
            }
            // se: og-redundant; lane bits 2-3 on DPP, 4-5 on swizzle
            se0 = dpp_add_shr4(se0);  se1 = dpp_add_shr4(se1);
            se0 = dpp_add_shr8(se0);  se1 = dpp_add_shr8(se1);
            se0 += __shfl_xor(se0, 16, 64);  se1 += __shfl_xor(se1, 16, 64);
            se0 += __shfl_xor(se0, 32, 64);  se1 += __shfl_xor(se1, 32, 64);
            if (lane == 15) { redE[wv][0] = se0; redE[wv][1] = se1; }
        }

        // s-reduce over the wave's 16 cr-slots: bits 2-3 via DPP row_shr
        // (og-preserving; totals in lanes 12..15), bits 4-5 via swizzle.
        s0.x = dpp_add_shr4(s0.x);  s1.x = dpp_add_shr4(s1.x);
        s0.y = dpp_add_shr4(s0.y);  s1.y = dpp_add_shr4(s1.y);
        s0.z = dpp_add_shr4(s0.z);  s1.z = dpp_add_shr4(s1.z);
        s0.w = dpp_add_shr4(s0.w);  s1.w = dpp_add_shr4(s1.w);
        s0.x = dpp_add_shr8(s0.x);  s1.x = dpp_add_shr8(s1.x);
        s0.y = dpp_add_shr8(s0.y);  s1.y = dpp_add_shr8(s1.y);
        s0.z = dpp_add_shr8(s0.z);  s1.z = dpp_add_shr8(s1.z);
        s0.w = dpp_add_shr8(s0.w);  s1.w = dpp_add_shr8(s1.w);
        #pragma unroll
        for (int off = 16; off <= 32; off <<= 1) {
            s0.x += __shfl_xor(s0.x, off, 64);  s1.x += __shfl_xor(s1.x, off, 64);
            s0.y += __shfl_xor(s0.y, off, 64);  s1.y += __shfl_xor(s1.y, off, 64);
            s0.z += __shfl_xor(s0.z, off, 64);  s1.z += __shfl_xor(s1.z, off, 64);
            s0.w += __shfl_xor(s0.w, off, 64);  s1.w += __shfl_xor(s1.w, off, 64);
        }
        if (lane >= 12 && lane < 16) {   // lanes 12..15, og = lane&3
            *(float4*)&sRed[wv][0][(lane & 3) * 4] = s0;
            *(float4*)&sRed[wv][1][(lane & 3) * 4] = s1;
        }
        __syncthreads();

        // ---- squash: 64 threads = (sub 0..3, o 0..15)
        if (tid < 64) {
            const int sub = tid >> 4;
            const int o   = tid & 15;
            const int g   = sub >> 1;      // wave-pair group
            const int l   = sub & 1;       // local sub within pair
            const float inv = (it == 0)
                ? (1.0f / (float)R_)
                : 1.0f / (redE[g * 2][l] + redE[g * 2 + 1][l]);
            float s = (sRed[g * 2][l][o] + sRed[g * 2 + 1][l][o]) * inv;
            float sn = s * s;
            sn = dpp_add_xor1(sn);
            sn = dpp_add_xor2(sn);
            sn += __shfl_xor(sn, 4, 64);
            sn += __shfl_xor(sn, 8, 64);
            const float v = s * (sqrtf(sn) / (1.0f + sn));
            if (it == NITER - 1) {
                out[((((size_t)(b0 + sub) * C_ + c) * W_ + p) * W_ + q) * COUT + o] = v;
            } else {
                vS[sub][o] = v;
            }
        }
        if (it == NITER - 1) break;
        __syncthreads();   // vS visible before next iteration
    }
}

extern "C" void kernel_launch(void* const* d_in, const int* in_sizes, int n_in,
                              void* d_out, int out_size, void* d_ws, size_t ws_size,
                              hipStream_t stream) {
    const float* x  = (const float*)d_in[0];
    const float* rw = (const float*)d_in[1];
    float* out = (float*)d_out;
    dim3 grid(W_ * W_, 2, C_);
    caps_routeC<<<grid, 256, 0, stream>>>(x, rw, out);
}